// Round 1
// baseline (37.732 us; speedup 1.0000x reference)
//
#include <hip/hip_runtime.h>

// Problem constants (fixed by reference: INPUT_SHAPE=(1,3,48,48), stride=2, pad=1)
#define OC   16
#define IC   3
#define KH   4
#define KW   4
#define IH   48
#define IW   48
#define STR  2
#define PAD  1
#define HO   24          // (48 + 2*1 - 4)/2 + 1
#define WO   24
#define NCOL (IC*IH*IW)  // 6912 flattened input size
#define NROW (OC*HO*WO)  // 9216 flattened output size
#define NC4  (NCOL/4)    // 1728 float4 per W row (IW=48 divisible by 4)

// One thread writes one float4 of W_mat. Row-major W_mat[NROW][NCOL].
__global__ void __launch_bounds__(256)
wmat_kernel(const float* __restrict__ kern, float* __restrict__ out) {
    int c4 = blockIdx.x * blockDim.x + threadIdx.x;
    if (c4 >= NC4) return;
    int row = blockIdx.y;                 // (o, oh, ow)
    int o   = row / (HO * WO);
    int rem = row - o * (HO * WO);
    int oh  = rem / WO;
    int ow  = rem - oh * WO;

    // col = c4*4 + j  ->  (c, h, w0+j); all 4 lanes share (c, h).
    int c  = c4 / (IH * IW / 4);          // / 576
    int r2 = c4 - c * (IH * IW / 4);
    int h  = r2 / (IW / 4);               // / 12
    int w0 = (r2 - h * (IW / 4)) * 4;

    int kh = h - (oh * STR - PAD);
    float4 v = make_float4(0.f, 0.f, 0.f, 0.f);
    if (kh >= 0 && kh < KH) {
        int kwb = w0 - (ow * STR - PAD);
        const float* kp = kern + ((size_t)(o * IC + c) * KH + kh) * KW;
        float x[4];
#pragma unroll
        for (int j = 0; j < 4; ++j) {
            int kw = kwb + j;
            x[j] = (kw >= 0 && kw < KW) ? kp[kw] : 0.f;
        }
        v = make_float4(x[0], x[1], x[2], x[3]);
    }
    reinterpret_cast<float4*>(out)[(size_t)row * NC4 + c4] = v;
}

// b_vec[row] = bias[row / (HO*WO)], appended after W_mat.
__global__ void __launch_bounds__(256)
bias_kernel(const float* __restrict__ bias, float* __restrict__ out) {
    int r = blockIdx.x * blockDim.x + threadIdx.x;
    if (r >= NROW) return;
    out[(size_t)NROW * NCOL + r] = bias[r / (HO * WO)];
}

extern "C" void kernel_launch(void* const* d_in, const int* in_sizes, int n_in,
                              void* d_out, int out_size, void* d_ws, size_t ws_size,
                              hipStream_t stream) {
    const float* kern = (const float*)d_in[0];   // (16,3,4,4) f32
    const float* bias = (const float*)d_in[1];   // (16,)      f32
    // d_in[2] = stride (=2), d_in[3] = padding (=1): fixed by setup_inputs; baked in.
    float* out = (float*)d_out;                  // 9216*6912 + 9216 floats

    dim3 block(256);
    dim3 gridW((NC4 + 255) / 256, NROW);         // (7, 9216)
    wmat_kernel<<<gridW, block, 0, stream>>>(kern, out);

    dim3 gridB((NROW + 255) / 256);              // 36 blocks
    bias_kernel<<<gridB, block, 0, stream>>>(bias, out);
}